// Round 1
// baseline (1937.414 us; speedup 1.0000x reference)
//
#include <hip/hip_runtime.h>
#include <cstddef>

#define B_    16
#define CIN_  256
#define COUT_ 128
#define H_    64
#define W_    64
#define OH_   128
#define OW_   128

// ---------------------------------------------------------------------------
// Kernel 1: synthesize per-sample weights into workspace.
// wsyn[b][ci][co][tap] = weight[ci,co,tap]
//   + f[b,0]*m_bayer[ci,co]*t_bayer[ci,co,tap] + ... (4 terms)
// Fully coalesced float4 over taps (16 taps per (ci,co) -> 4 float4).
// ---------------------------------------------------------------------------
__global__ __launch_bounds__(256) void synth_kernel(
    const float* __restrict__ weight,
    const float* __restrict__ tb, const float* __restrict__ tq,
    const float* __restrict__ tn, const float* __restrict__ tx,
    const float* __restrict__ mb, const float* __restrict__ mq,
    const float* __restrict__ mn, const float* __restrict__ mx,
    const float* __restrict__ feat,
    float* __restrict__ wsyn)
{
    const int perb4 = CIN_ * COUT_ * 4;        // float4 count per sample
    int g  = blockIdx.x * 256 + threadIdx.x;   // global float4 index (exact grid)
    int b  = g / perb4;
    int r4 = g - b * perb4;                    // float4 idx within sample
    int cico = r4 >> 2;                        // (ci*COUT + co)

    float4 w  = ((const float4*)weight)[r4];
    float4 vb = ((const float4*)tb)[r4];
    float4 vq = ((const float4*)tq)[r4];
    float4 vn = ((const float4*)tn)[r4];
    float4 vx = ((const float4*)tx)[r4];
    float sb = mb[cico] * feat[b*4 + 0];
    float sq = mq[cico] * feat[b*4 + 1];
    float sn = mn[cico] * feat[b*4 + 2];
    float sx = mx[cico] * feat[b*4 + 3];
    float4 o;
    o.x = w.x + sb*vb.x + sq*vq.x + sn*vn.x + sx*vx.x;
    o.y = w.y + sb*vb.y + sq*vq.y + sn*vn.y + sx*vx.y;
    o.z = w.z + sb*vb.z + sq*vq.z + sn*vn.z + sx*vx.z;
    o.w = w.w + sb*vb.w + sq*vq.w + sn*vn.w + sx*vx.w;
    ((float4*)wsyn)[g] = o;
}

// ---------------------------------------------------------------------------
// Kernel 2: direct transposed conv.
// out[b,co,oh,ow] = sum_{ci,kh,kw valid} w[b,ci,co,kh,kw] * x[b,ci,ih,iw]
//   ih = (oh+1-kh)/2 when integral & in [0,64); same for iw.
// Tap -> (row parity r, patch-row offset): kh=0:(r=1,off=2) kh=1:(r=0,off=1)
//                                          kh=2:(r=1,off=1) kh=3:(r=0,off=0)
// Block: 256 thr. Tile: 64 co x 16x16 out pixels. Thread: 4 co x 4x4 pixels.
// ---------------------------------------------------------------------------
template<bool SYNTH>
__global__ __launch_bounds__(256) void deconv_kernel(
    const float* __restrict__ x,
    const float* __restrict__ wsyn,
    const float* __restrict__ weight,
    const float* __restrict__ tb, const float* __restrict__ tq,
    const float* __restrict__ tn, const float* __restrict__ tx,
    const float* __restrict__ mb, const float* __restrict__ mq,
    const float* __restrict__ mn, const float* __restrict__ mx,
    const float* __restrict__ feat,
    const float* __restrict__ bias, const float* __restrict__ prelu_a,
    float* __restrict__ out)
{
    const int tid    = threadIdx.x;
    const int tile   = blockIdx.x;          // 0..63 -> 8x8 spatial tiles
    const int coT    = blockIdx.y;          // 0..1
    const int b      = blockIdx.z;          // 0..15
    const int tile_h = tile >> 3, tile_w = tile & 7;
    const int a0 = tile_h * 8;              // input-row base of tile (a units)
    const int c0 = tile_w * 8;
    const int co0 = coT * 64;

    const int tco = tid & 15;               // 16 co-groups of 4 co
    const int tpx = tid >> 4;               // 16 pixel groups (4x4 regions)
    const int rr  = tpx >> 2, rc = tpx & 3;

    __shared__ float xs[4][100];            // [ci][10*10] halo tile
    __shared__ float wsh[4][16][64];        // [ci][tap][co] transposed

    float acc[4][4][4];                     // [dr][dw][cc]
    #pragma unroll
    for (int i = 0; i < 4; ++i)
        #pragma unroll
        for (int j = 0; j < 4; ++j)
            #pragma unroll
            for (int c = 0; c < 4; ++c) acc[i][j][c] = 0.f;

    float f0 = 0.f, f1 = 0.f, f2 = 0.f, f3 = 0.f;
    if (SYNTH) {
        f0 = feat[b*4 + 0]; f1 = feat[b*4 + 1];
        f2 = feat[b*4 + 2]; f3 = feat[b*4 + 3];
    }

    for (int chunk = 0; chunk < CIN_ / 4; ++chunk) {
        const int ci0 = chunk * 4;
        __syncthreads();
        // ---- stage x halo tile (4 ci x 10x10, zero-padded at borders) ----
        for (int e = tid; e < 400; e += 256) {
            int ci_l = e / 100; int rem = e - ci_l * 100;
            int rI = rem / 10;  int cI = rem - rI * 10;
            int ih = a0 - 1 + rI, iw = c0 - 1 + cI;
            float v = 0.f;
            if ((unsigned)ih < (unsigned)H_ && (unsigned)iw < (unsigned)W_)
                v = x[(((size_t)b * CIN_ + ci0 + ci_l) * H_ + ih) * W_ + iw];
            xs[ci_l][rem] = v;
        }
        // ---- stage weights (4 ci x 64 co x 16 taps), transpose to [tap][co] ----
        #pragma unroll
        for (int k = 0; k < 4; ++k) {
            int g = tid + k * 256;          // float4 index, 0..1023
            int ci_l = g >> 8; int r = g & 255;
            int co_l = r >> 2; int tg = (r & 3) * 4;
            int cico = (ci0 + ci_l) * COUT_ + co0 + co_l;
            float4 wv;
            if (!SYNTH) {
                wv = *(const float4*)(wsyn + (size_t)b * (CIN_ * COUT_ * 16)
                                           + (size_t)cico * 16 + tg);
            } else {
                int e = cico * 16 + tg;
                float4 w  = *(const float4*)(weight + e);
                float4 vb = *(const float4*)(tb + e);
                float4 vq = *(const float4*)(tq + e);
                float4 vn = *(const float4*)(tn + e);
                float4 vx = *(const float4*)(tx + e);
                float sb = mb[cico] * f0, sq = mq[cico] * f1;
                float sn = mn[cico] * f2, sx = mx[cico] * f3;
                wv.x = w.x + sb*vb.x + sq*vq.x + sn*vn.x + sx*vx.x;
                wv.y = w.y + sb*vb.y + sq*vq.y + sn*vn.y + sx*vx.y;
                wv.z = w.z + sb*vb.z + sq*vq.z + sn*vn.z + sx*vx.z;
                wv.w = w.w + sb*vb.w + sq*vq.w + sn*vn.w + sx*vx.w;
            }
            wsh[ci_l][tg + 0][co_l] = wv.x;
            wsh[ci_l][tg + 1][co_l] = wv.y;
            wsh[ci_l][tg + 2][co_l] = wv.z;
            wsh[ci_l][tg + 3][co_l] = wv.w;
        }
        __syncthreads();
        // ---- accumulate ----
        #pragma unroll
        for (int ci_l = 0; ci_l < 4; ++ci_l) {
            float xp[4][4];                 // rows ih = a0t-1+i, cols iw = c0t-1+j
            #pragma unroll
            for (int i = 0; i < 4; ++i)
                #pragma unroll
                for (int j = 0; j < 4; ++j)
                    xp[i][j] = xs[ci_l][(rr*2 + i) * 10 + rc*2 + j];
            #pragma unroll
            for (int kh = 0; kh < 4; ++kh) {
                const int r    = (kh & 1) ? 0 : 1;
                const int offh = (kh == 0) ? 2 : (kh == 3) ? 0 : 1;
                #pragma unroll
                for (int kw = 0; kw < 4; ++kw) {
                    const int s    = (kw & 1) ? 0 : 1;
                    const int offw = (kw == 0) ? 2 : (kw == 3) ? 0 : 1;
                    float4 wvv = *(const float4*)&wsh[ci_l][kh*4 + kw][tco*4];
                    float wr[4] = {wvv.x, wvv.y, wvv.z, wvv.w};
                    #pragma unroll
                    for (int da = 0; da < 2; ++da)
                        #pragma unroll
                        for (int dc = 0; dc < 2; ++dc) {
                            const float xv = xp[da + offh][dc + offw];
                            #pragma unroll
                            for (int cc = 0; cc < 4; ++cc)
                                acc[2*da + r][2*dc + s][cc] =
                                    fmaf(wr[cc], xv, acc[2*da + r][2*dc + s][cc]);
                        }
                }
            }
        }
    }
    // ---- epilogue: bias + PReLU, scalar stores ----
    const float pa  = prelu_a[0];
    const int oh0 = tile_h * 16 + rr * 4;
    const int ow0 = tile_w * 16 + rc * 4;
    #pragma unroll
    for (int cc = 0; cc < 4; ++cc) {
        const int co = co0 + tco * 4 + cc;
        const float bv = bias[co];
        #pragma unroll
        for (int dr = 0; dr < 4; ++dr)
            #pragma unroll
            for (int dw = 0; dw < 4; ++dw) {
                float v = acc[dr][dw][cc] + bv;
                v = (v >= 0.f) ? v : pa * v;
                out[(((size_t)b * COUT_ + co) * OH_ + (oh0 + dr)) * OW_ + (ow0 + dw)] = v;
            }
    }
}

extern "C" void kernel_launch(void* const* d_in, const int* in_sizes, int n_in,
                              void* d_out, int out_size, void* d_ws, size_t ws_size,
                              hipStream_t stream) {
    (void)in_sizes; (void)n_in; (void)out_size;
    const float* x      = (const float*)d_in[0];
    const float* feat   = (const float*)d_in[1];
    const float* weight = (const float*)d_in[2];
    const float* tb     = (const float*)d_in[3];
    const float* tq     = (const float*)d_in[4];
    const float* tn     = (const float*)d_in[5];
    const float* tx     = (const float*)d_in[6];
    const float* mb     = (const float*)d_in[7];
    const float* mq     = (const float*)d_in[8];
    const float* mn     = (const float*)d_in[9];
    const float* mx     = (const float*)d_in[10];
    const float* bias   = (const float*)d_in[11];
    const float* prelu  = (const float*)d_in[12];
    float* out = (float*)d_out;

    const size_t need = (size_t)B_ * CIN_ * COUT_ * 16 * sizeof(float);
    dim3 grid(64, 2, 16);
    if (ws_size >= need) {
        float* wsyn = (float*)d_ws;
        synth_kernel<<<(B_ * CIN_ * COUT_ * 4) / 256, 256, 0, stream>>>(
            weight, tb, tq, tn, tx, mb, mq, mn, mx, feat, wsyn);
        deconv_kernel<false><<<grid, 256, 0, stream>>>(
            x, wsyn, weight, tb, tq, tn, tx, mb, mq, mn, mx, feat, bias, prelu, out);
    } else {
        deconv_kernel<true><<<grid, 256, 0, stream>>>(
            x, nullptr, weight, tb, tq, tn, tx, mb, mq, mn, mx, feat, bias, prelu, out);
    }
}

// Round 2
// 402.890 us; speedup vs baseline: 4.8088x; 4.8088x over previous
//
#include <hip/hip_runtime.h>
#include <hip/hip_bf16.h>
#include <cstddef>
#include <cstdint>

#define B_    16
#define CIN_  256
#define COUT_ 128
#define H_    64
#define W_    64
#define OH_   128
#define OW_   128

typedef __attribute__((ext_vector_type(8))) short bf16x8;
typedef __attribute__((ext_vector_type(4))) float f32x4;

__device__ inline short f2bf(float f) {
    __hip_bfloat16 h = __float2bfloat16(f);
    return *reinterpret_cast<short*>(&h);
}

__device__ inline void async_ld16(const void* g, void* l) {
    typedef const __attribute__((address_space(1))) unsigned int* gp_t;
    typedef __attribute__((address_space(3))) unsigned int* lp_t;
    __builtin_amdgcn_global_load_lds((gp_t)g, (lp_t)l, 16, 0, 0);
}

// ---------------------------------------------------------------------------
// Kernel 1: synthesize per-(b,class) weight matrices in MFMA A-layout.
// aws[b][class(4)][chunk(32)][co(128)][40] bf16, where entry [k_local] for
// k_local = t*8 + ci_l (t = dh*2+dw) holds wsyn[b, chunk*8+ci_l, co, kh, kw]:
//   kh: (r,dh) -> kh(0,0)=3 kh(0,1)=1 kh(1,0)=2 kh(1,1)=0  (same for kw/s/dw)
//   i.e. given kh: r=(kh+1)&1, dh = (kh<2);  class = r*2+s.
// k_local 32..39 is padding (garbage, never read as a fragment).
// ---------------------------------------------------------------------------
__global__ __launch_bounds__(256) void synth_aws(
    const float* __restrict__ weight,
    const float* __restrict__ tb, const float* __restrict__ tq,
    const float* __restrict__ tn, const float* __restrict__ tx,
    const float* __restrict__ mb, const float* __restrict__ mq,
    const float* __restrict__ mn, const float* __restrict__ mx,
    const float* __restrict__ feat,
    short* __restrict__ aws)
{
    const int chunk = blockIdx.x;     // 0..31
    const int b     = blockIdx.y;     // 0..15
    const int tid   = threadIdx.x;
    const int ci0   = chunk * 8;

    __shared__ __align__(16) short lbuf[4][128][40];   // 40960 B

    const float f0 = feat[b*4+0], f1 = feat[b*4+1];
    const float f2 = feat[b*4+2], f3 = feat[b*4+3];

    for (int it = 0; it < 16; ++it) {
        int e4   = tid + it*256;          // 0..4095: (ci_l, co, kh)
        int ci_l = e4 >> 9;
        int rem  = e4 & 511;
        int co   = rem >> 2;
        int kh   = rem & 3;
        int base = (ci0 + ci_l) * COUT_ + co;
        const float* wv = (const float*)(weight + (size_t)base*16 + kh*4);
        const float* bv = (const float*)(tb + (size_t)base*16 + kh*4);
        const float* qv = (const float*)(tq + (size_t)base*16 + kh*4);
        const float* nv = (const float*)(tn + (size_t)base*16 + kh*4);
        const float* xv = (const float*)(tx + (size_t)base*16 + kh*4);
        float4 w4 = *(const float4*)wv;
        float4 b4 = *(const float4*)bv;
        float4 q4 = *(const float4*)qv;
        float4 n4 = *(const float4*)nv;
        float4 x4 = *(const float4*)xv;
        const float* wp = (const float*)&w4;
        const float* bp = (const float*)&b4;
        const float* qp = (const float*)&q4;
        const float* np = (const float*)&n4;
        const float* xp = (const float*)&x4;
        float sb = mb[base]*f0, sq = mq[base]*f1;
        float sn = mn[base]*f2, sx = mx[base]*f3;
        int r  = (kh+1)&1;
        int dh = (kh<2) ? 1 : 0;
        #pragma unroll
        for (int kw = 0; kw < 4; ++kw) {
            int s  = (kw+1)&1;
            int dw = (kw<2) ? 1 : 0;
            float v = wp[kw] + sb*bp[kw] + sq*qp[kw] + sn*np[kw] + sx*xp[kw];
            lbuf[r*2+s][co][(dh*2+dw)*8 + ci_l] = f2bf(v);
        }
    }
    __syncthreads();
    // coalesced copy-out: per class a contiguous 10240 B slice
    #pragma unroll
    for (int cls = 0; cls < 4; ++cls) {
        size_t dst = ((((size_t)b*4 + cls)*32 + chunk)) * (128*40);
        const short* srcp = &lbuf[cls][0][0];
        for (int j = tid; j < 640; j += 256) {          // 640 x 16B
            *(int4*)(aws + dst + (size_t)j*8) = *(const int4*)(srcp + j*8);
        }
    }
}

// ---------------------------------------------------------------------------
// Kernel 2: MFMA implicit-GEMM deconv, one (b, class, 128co x 128px) per block.
// out[b,co,2a+r,2c+s] = sum_{ci,dh,dw} A[b,cls][k=(dh*2+dw)*8+ci%8, chunk=ci/8][co]
//                                      * x[b,ci,a-1+r+dh, c-1+s+dw]
// Block px tile: 8 a-rows x 16 cols. Waves 2(m) x 2(n). K-chunks of 32 (8 ci).
// ---------------------------------------------------------------------------
__global__ __launch_bounds__(256, 2) void deconv_mfma(
    const float* __restrict__ x,
    const short* __restrict__ aws,
    const float* __restrict__ bias,
    const float* __restrict__ prelu_a,
    float* __restrict__ out)
{
    const int tid  = threadIdx.x;
    const int lane = tid & 63;
    const int wv   = tid >> 6;          // wave 0..3
    const int wm   = wv & 1, wn = wv >> 1;
    const int nt   = blockIdx.x;        // 0..31
    const int cls  = blockIdx.y;        // 0..3
    const int b    = blockIdx.z;        // 0..15
    const int a_blk = nt >> 2, c_blk = nt & 3;
    const int a0 = a_blk * 8, c0 = c_blk * 16;
    const int r = cls >> 1, s = cls & 1;

    __shared__ __align__(16) short xs[1280];   // [row(9)][col(17)][ci_l(8)] + dump
    __shared__ __align__(16) short als[5120];  // [co(128)][40]

    // ---- per-thread gather plan (chunk-invariant) ----
    int goff[5], gstep[5], gok[5];
    #pragma unroll
    for (int i = 0; i < 5; ++i) {
        int e    = tid + i*256;          // xs flat index
        int ci_l = e & 7;
        int rc   = e >> 3;               // 0..159
        int row  = rc / 17;
        int col  = rc - row*17;
        int ih   = a0 - 1 + r + row;
        int iw   = c0 - 1 + s + col;
        int ok   = (rc < 153) && ((unsigned)ih < (unsigned)H_)
                              && ((unsigned)iw < (unsigned)W_);
        goff[i]  = ok ? (((b*CIN_ + ci_l)*H_ + ih)*W_ + iw) : 0;
        gstep[i] = ok ? (8*H_*W_) : 0;
        gok[i]   = ok;
    }
    const size_t aws_base = (((size_t)b*4 + cls)*32) * 5120;

    f32x4 acc[4][4];
    #pragma unroll
    for (int mi = 0; mi < 4; ++mi)
        #pragma unroll
        for (int ni = 0; ni < 4; ++ni)
            acc[mi][ni] = (f32x4){0.f, 0.f, 0.f, 0.f};

    const int nlo = lane & 15;           // m index (A) / n index (B,D)
    const int q   = lane >> 4;           // quad: k-group, and tap t for B
    const int dh  = q >> 1, dw = q & 1;

    for (int chunk = 0; chunk < 32; ++chunk) {
        __syncthreads();
        // ---- stage x tile (fp32 -> bf16 gather; plan precomputed) ----
        #pragma unroll
        for (int i = 0; i < 5; ++i) {
            float v = x[goff[i] + chunk*gstep[i]];
            v = gok[i] ? v : 0.0f;
            xs[tid + i*256] = f2bf(v);
        }
        // ---- stage A tile via async global->LDS (10 x 1KB wave transfers) ----
        {
            const short* src = aws + aws_base + (size_t)chunk*5120;
            #pragma unroll
            for (int i = 0; i < 3; ++i) {
                int idx = wv + i*4;
                if (idx < 10)
                    async_ld16(src + idx*512 + lane*8, als + idx*512);
            }
        }
        __syncthreads();
        // ---- fragments + MFMA ----
        bf16x8 af[4], bfr[4];
        #pragma unroll
        for (int mi = 0; mi < 4; ++mi)
            af[mi] = *(const bf16x8*)(als + (wm*64 + mi*16 + nlo)*40 + q*8);
        #pragma unroll
        for (int ni = 0; ni < 4; ++ni) {
            int a_local = wn*4 + ni;
            bfr[ni] = *(const bf16x8*)(xs + ((a_local + dh)*17 + (nlo + dw))*8);
        }
        #pragma unroll
        for (int mi = 0; mi < 4; ++mi)
            #pragma unroll
            for (int ni = 0; ni < 4; ++ni)
                acc[mi][ni] = __builtin_amdgcn_mfma_f32_16x16x32_bf16(
                    af[mi], bfr[ni], acc[mi][ni], 0, 0, 0);
    }

    // ---- epilogue: bias + PReLU ----
    const float pa = prelu_a[0];
    #pragma unroll
    for (int mi = 0; mi < 4; ++mi) {
        #pragma unroll
        for (int reg = 0; reg < 4; ++reg) {
            int co = wm*64 + mi*16 + q*4 + reg;
            float bv = bias[co];
            #pragma unroll
            for (int ni = 0; ni < 4; ++ni) {
                int a_local = wn*4 + ni;
                int oh = 2*(a0 + a_local) + r;
                int ow = 2*(c0 + nlo) + s;
                float v = acc[mi][ni][reg] + bv;
                v = (v >= 0.f) ? v : pa*v;
                out[(((size_t)b*COUT_ + co)*OH_ + oh)*OW_ + ow] = v;
            }
        }
    }
}

// ---------------------------------------------------------------------------
// Fallback (round-1 fp32 direct kernel, in-kernel weight synthesis, no ws).
// ---------------------------------------------------------------------------
__global__ __launch_bounds__(256) void deconv_fallback(
    const float* __restrict__ x,
    const float* __restrict__ weight,
    const float* __restrict__ tb, const float* __restrict__ tq,
    const float* __restrict__ tn, const float* __restrict__ tx,
    const float* __restrict__ mb, const float* __restrict__ mq,
    const float* __restrict__ mn, const float* __restrict__ mx,
    const float* __restrict__ feat,
    const float* __restrict__ bias, const float* __restrict__ prelu_a,
    float* __restrict__ out)
{
    const int tid    = threadIdx.x;
    const int tile   = blockIdx.x;
    const int coT    = blockIdx.y;
    const int b      = blockIdx.z;
    const int tile_h = tile >> 3, tile_w = tile & 7;
    const int a0 = tile_h * 8;
    const int c0 = tile_w * 8;
    const int co0 = coT * 64;

    const int tco = tid & 15;
    const int tpx = tid >> 4;
    const int rr  = tpx >> 2, rc = tpx & 3;

    __shared__ float xsf[4][100];
    __shared__ float wsh[4][16][64];

    float acc[4][4][4];
    #pragma unroll
    for (int i = 0; i < 4; ++i)
        #pragma unroll
        for (int j = 0; j < 4; ++j)
            #pragma unroll
            for (int c = 0; c < 4; ++c) acc[i][j][c] = 0.f;

    float f0 = feat[b*4 + 0], f1 = feat[b*4 + 1];
    float f2 = feat[b*4 + 2], f3 = feat[b*4 + 3];

    for (int chunk = 0; chunk < CIN_ / 4; ++chunk) {
        const int ci0 = chunk * 4;
        __syncthreads();
        for (int e = tid; e < 400; e += 256) {
            int ci_l = e / 100; int rem = e - ci_l * 100;
            int rI = rem / 10;  int cI = rem - rI * 10;
            int ih = a0 - 1 + rI, iw = c0 - 1 + cI;
            float v = 0.f;
            if ((unsigned)ih < (unsigned)H_ && (unsigned)iw < (unsigned)W_)
                v = x[(((size_t)b * CIN_ + ci0 + ci_l) * H_ + ih) * W_ + iw];
            xsf[ci_l][rem] = v;
        }
        #pragma unroll
        for (int k = 0; k < 4; ++k) {
            int g = tid + k * 256;
            int ci_l = g >> 8; int rrem = g & 255;
            int co_l = rrem >> 2; int tg = (rrem & 3) * 4;
            int cico = (ci0 + ci_l) * COUT_ + co0 + co_l;
            int e = cico * 16 + tg;
            float4 w  = *(const float4*)(weight + e);
            float4 vb = *(const float4*)(tb + e);
            float4 vq = *(const float4*)(tq + e);
            float4 vn = *(const float4*)(tn + e);
            float4 vx = *(const float4*)(tx + e);
            float sb = mb[cico] * f0, sq = mq[cico] * f1;
            float sn = mn[cico] * f2, sx = mx[cico] * f3;
            float4 wvv;
            wvv.x = w.x + sb*vb.x + sq*vq.x + sn*vn.x + sx*vx.x;
            wvv.y = w.y + sb*vb.y + sq*vq.y + sn*vn.y + sx*vx.y;
            wvv.z = w.z + sb*vb.z + sq*vq.z + sn*vn.z + sx*vx.z;
            wvv.w = w.w + sb*vb.w + sq*vq.w + sn*vn.w + sx*vx.w;
            wsh[ci_l][tg + 0][co_l] = wvv.x;
            wsh[ci_l][tg + 1][co_l] = wvv.y;
            wsh[ci_l][tg + 2][co_l] = wvv.z;
            wsh[ci_l][tg + 3][co_l] = wvv.w;
        }
        __syncthreads();
        #pragma unroll
        for (int ci_l = 0; ci_l < 4; ++ci_l) {
            float xpv[4][4];
            #pragma unroll
            for (int i = 0; i < 4; ++i)
                #pragma unroll
                for (int j = 0; j < 4; ++j)
                    xpv[i][j] = xsf[ci_l][(rr*2 + i) * 10 + rc*2 + j];
            #pragma unroll
            for (int kh = 0; kh < 4; ++kh) {
                const int rpar = (kh & 1) ? 0 : 1;
                const int offh = (kh == 0) ? 2 : (kh == 3) ? 0 : 1;
                #pragma unroll
                for (int kw = 0; kw < 4; ++kw) {
                    const int spar = (kw & 1) ? 0 : 1;
                    const int offw = (kw == 0) ? 2 : (kw == 3) ? 0 : 1;
                    float4 wvv = *(const float4*)&wsh[ci_l][kh*4 + kw][tco*4];
                    float wr[4] = {wvv.x, wvv.y, wvv.z, wvv.w};
                    #pragma unroll
                    for (int da = 0; da < 2; ++da)
                        #pragma unroll
                        for (int dc = 0; dc < 2; ++dc) {
                            const float xvv = xpv[da + offh][dc + offw];
                            #pragma unroll
                            for (int cc = 0; cc < 4; ++cc)
                                acc[2*da + rpar][2*dc + spar][cc] =
                                    fmaf(wr[cc], xvv, acc[2*da + rpar][2*dc + spar][cc]);
                        }
                }
            }
        }
    }
    const float pa  = prelu_a[0];
    const int oh0 = tile_h * 16 + rr * 4;
    const int ow0 = tile_w * 16 + rc * 4;
    #pragma unroll
    for (int cc = 0; cc < 4; ++cc) {
        const int co = co0 + tco * 4 + cc;
        const float bv = bias[co];
        #pragma unroll
        for (int dr = 0; dr < 4; ++dr)
            #pragma unroll
            for (int dw2 = 0; dw2 < 4; ++dw2) {
                float v = acc[dr][dw2][cc] + bv;
                v = (v >= 0.f) ? v : pa * v;
                out[(((size_t)b * COUT_ + co) * OH_ + (oh0 + dr)) * OW_ + (ow0 + dw2)] = v;
            }
    }
}

extern "C" void kernel_launch(void* const* d_in, const int* in_sizes, int n_in,
                              void* d_out, int out_size, void* d_ws, size_t ws_size,
                              hipStream_t stream) {
    (void)in_sizes; (void)n_in; (void)out_size;
    const float* x      = (const float*)d_in[0];
    const float* feat   = (const float*)d_in[1];
    const float* weight = (const float*)d_in[2];
    const float* tb     = (const float*)d_in[3];
    const float* tq     = (const float*)d_in[4];
    const float* tn     = (const float*)d_in[5];
    const float* tx     = (const float*)d_in[6];
    const float* mb     = (const float*)d_in[7];
    const float* mq     = (const float*)d_in[8];
    const float* mn     = (const float*)d_in[9];
    const float* mx     = (const float*)d_in[10];
    const float* bias   = (const float*)d_in[11];
    const float* prelu  = (const float*)d_in[12];
    float* out = (float*)d_out;

    const size_t need = (size_t)B_ * 4 * 32 * 128 * 40 * sizeof(short);  // 20.97 MB
    if (ws_size >= need) {
        short* aws = (short*)d_ws;
        synth_aws<<<dim3(32, 16), 256, 0, stream>>>(
            weight, tb, tq, tn, tx, mb, mq, mn, mx, feat, aws);
        deconv_mfma<<<dim3(32, 4, 16), 256, 0, stream>>>(
            x, aws, bias, prelu, out);
    } else {
        deconv_fallback<<<dim3(64, 2, 16), 256, 0, stream>>>(
            x, weight, tb, tq, tn, tx, mb, mq, mn, mx, feat, bias, prelu, out);
    }
}

// Round 3
// 293.503 us; speedup vs baseline: 6.6010x; 1.3727x over previous
//
#include <hip/hip_runtime.h>
#include <hip/hip_bf16.h>
#include <cstddef>
#include <cstdint>

#define B_    16
#define CIN_  256
#define COUT_ 128
#define H_    64
#define W_    64
#define OH_   128
#define OW_   128

typedef __attribute__((ext_vector_type(8))) short bf16x8;
typedef __attribute__((ext_vector_type(4))) float f32x4;

__device__ inline short f2bf(float f) {
    __hip_bfloat16 h = __float2bfloat16(f);
    return *reinterpret_cast<short*>(&h);
}

__device__ inline void async_ld16(const void* g, void* l) {
    typedef const __attribute__((address_space(1))) unsigned int* gp_t;
    typedef __attribute__((address_space(3))) unsigned int* lp_t;
    __builtin_amdgcn_global_load_lds((gp_t)g, (lp_t)l, 16, 0, 0);
}

// ---------------------------------------------------------------------------
// Kernel A: synthesize per-(b,class) weight matrices in MFMA A-layout.
// aws[b][cls(4)][chunk(32)][co(128)][40] bf16; k_local = t*8 + ci_l,
// t = dh*2+dw; kh -> r=(kh+1)&1, dh=(kh<2); cls = r*2+s. 32..39 = pad.
// v2: 32 co per block (grid x4), 4 iterations, 10 KB LDS -> latency hidden.
// ---------------------------------------------------------------------------
__global__ __launch_bounds__(256) void synth_aws(
    const float* __restrict__ weight,
    const float* __restrict__ tb, const float* __restrict__ tq,
    const float* __restrict__ tn, const float* __restrict__ tx,
    const float* __restrict__ mb, const float* __restrict__ mq,
    const float* __restrict__ mn, const float* __restrict__ mx,
    const float* __restrict__ feat,
    short* __restrict__ aws)
{
    const int chunk = blockIdx.x;     // 0..31
    const int cog   = blockIdx.y;     // 0..3 (co group of 32)
    const int b     = blockIdx.z;     // 0..15
    const int tid   = threadIdx.x;
    const int ci0   = chunk * 8;

    __shared__ __align__(16) short lbuf[4][32][40];   // 10240 B

    const float f0 = feat[b*4+0], f1 = feat[b*4+1];
    const float f2 = feat[b*4+2], f3 = feat[b*4+3];

    #pragma unroll
    for (int it = 0; it < 4; ++it) {
        int e4   = tid + it*256;          // 0..1023: (ci_l, co_l, kh)
        int ci_l = e4 >> 7;
        int rem  = e4 & 127;
        int co_l = rem >> 2;
        int kh   = rem & 3;
        int co   = cog*32 + co_l;
        int base = (ci0 + ci_l) * COUT_ + co;
        float4 w4 = *(const float4*)(weight + (size_t)base*16 + kh*4);
        float4 b4 = *(const float4*)(tb + (size_t)base*16 + kh*4);
        float4 q4 = *(const float4*)(tq + (size_t)base*16 + kh*4);
        float4 n4 = *(const float4*)(tn + (size_t)base*16 + kh*4);
        float4 x4 = *(const float4*)(tx + (size_t)base*16 + kh*4);
        const float* wp = (const float*)&w4;
        const float* bp = (const float*)&b4;
        const float* qp = (const float*)&q4;
        const float* np = (const float*)&n4;
        const float* xp = (const float*)&x4;
        float sb = mb[base]*f0, sq = mq[base]*f1;
        float sn = mn[base]*f2, sx = mx[base]*f3;
        int r  = (kh+1)&1;
        int dh = (kh<2) ? 1 : 0;
        #pragma unroll
        for (int kw = 0; kw < 4; ++kw) {
            int s  = (kw+1)&1;
            int dw = (kw<2) ? 1 : 0;
            float v = wp[kw] + sb*bp[kw] + sq*qp[kw] + sn*np[kw] + sx*xp[kw];
            lbuf[r*2+s][co_l][(dh*2+dw)*8 + ci_l] = f2bf(v);
        }
    }
    __syncthreads();
    // coalesced copy-out: per cls a contiguous 2560 B slice at co=cog*32
    for (int j = tid; j < 640; j += 256) {            // 640 x 16B
        int cls = j / 160; int jj = j - cls*160;
        size_t dst = (((size_t)(b*4 + cls)*32 + chunk)*128 + cog*32) * 40;
        *(int4*)(aws + dst + (size_t)jj*8) = *(const int4*)(&lbuf[cls][0][0] + jj*8);
    }
}

// ---------------------------------------------------------------------------
// Kernel B: transform x (fp32 NCHW) -> x_t bf16 [b][chunk32][ihp66][iwp66][ci8]
// with zero halo (ihp/iwp = padded coords = ih+1/iw+1).
// ---------------------------------------------------------------------------
__global__ __launch_bounds__(256) void transform_x(
    const float* __restrict__ x, short* __restrict__ xt)
{
    const int ihp = blockIdx.x;   // 0..65
    const int b   = blockIdx.y;
    const int tid = threadIdx.x;
    const int4 z4 = {0, 0, 0, 0};

    if (ihp == 0 || ihp == 65) {       // border rows: zero all chunks/cols
        for (int j = tid; j < 2112; j += 256) {       // 32 chunks * 66 cols
            int c = j / 66, iwp = j - c*66;
            *(int4*)(xt + ((((size_t)b*32 + c)*66 + ihp)*66 + iwp)*8) = z4;
        }
        return;
    }
    if (tid < 64) {                    // border cols iwp in {0,65}
        int c = tid >> 1, iwp = (tid & 1) * 65;
        *(int4*)(xt + ((((size_t)b*32 + c)*66 + ihp)*66 + iwp)*8) = z4;
    }
    const int ih = ihp - 1;
    __shared__ float xls[128][64];     // 32 KB
    for (int half = 0; half < 2; ++half) {
        __syncthreads();
        #pragma unroll 4
        for (int it = 0; it < 32; ++it) {
            int ci_l = it*4 + (tid >> 6);
            xls[ci_l][tid & 63] =
                x[(((size_t)b*256 + half*128 + ci_l)*64 + ih)*64 + (tid & 63)];
        }
        __syncthreads();
        #pragma unroll
        for (int it2 = 0; it2 < 4; ++it2) {
            int chunk_l = it2*4 + (tid >> 6);
            int chunk   = half*16 + chunk_l;
            int iw      = tid & 63;
            short s8[8];
            #pragma unroll
            for (int j = 0; j < 8; ++j) s8[j] = f2bf(xls[chunk_l*8 + j][iw]);
            *(int4*)(xt + ((((size_t)b*32 + chunk)*66 + ihp)*66 + (iw+1))*8)
                = *(const int4*)s8;
        }
    }
}

// ---------------------------------------------------------------------------
// Kernel C: MFMA deconv, all staging via async global_load_lds, double-buffer.
// Block: (nt, cls, b); 128 co x (8 a-rows x 16 cols) px; 32 K-chunks of 32.
// Per chunk: A = 10 x 1KB wave-transfers, B = 3 x 1KB (x_t tile 9x17 px x 8ci).
// ---------------------------------------------------------------------------
__global__ __launch_bounds__(256) void deconv_mfma2(
    const short* __restrict__ aws, const short* __restrict__ xt,
    const float* __restrict__ bias, const float* __restrict__ prelu_a,
    float* __restrict__ out)
{
    const int tid  = threadIdx.x;
    const int lane = tid & 63;
    const int wv   = tid >> 6;
    const int wm   = wv & 1, wn = wv >> 1;
    const int nt   = blockIdx.x;        // 0..31
    const int cls  = blockIdx.y;        // 0..3
    const int b    = blockIdx.z;        // 0..15
    const int a0 = (nt >> 2) * 8, c0 = (nt & 3) * 16;
    const int r = cls >> 1, s = cls & 1;

    __shared__ __align__(16) short als[2][5120];   // A: [co(128)][40]
    __shared__ __align__(16) short xsb[2][1536];   // B: [row9][col17][ci8]+pad

    // ---- per-thread staging plan: transfer t = wv + i*4; t<10 -> A, else B ----
    const short* gb[4]; int gstep[4], loff[4], isB[4], act[4];
    {
        const size_t awb = (((size_t)b*4 + cls)*32) * 5120;
        #pragma unroll
        for (int i = 0; i < 4; ++i) {
            int t = wv + i*4;
            act[i] = (t < 13);
            if (t < 10) {
                gb[i]    = aws + awb + t*512 + lane*8;
                gstep[i] = 5120;  loff[i] = t*512;  isB[i] = 0;
            } else {
                int j = t - 10;                     // 0..2 (garbage if !act)
                int p = j*64 + lane; if (p > 152) p = 152;
                int row = p / 17, col = p - row*17;
                gb[i] = xt + (((size_t)b*32*66 + (a0 + r + row))*66
                              + (c0 + s + col)) * 8;
                gstep[i] = 66*66*8;  loff[i] = j*512;  isB[i] = 1;
            }
        }
    }

    f32x4 acc[4][4];
    #pragma unroll
    for (int mi = 0; mi < 4; ++mi)
        #pragma unroll
        for (int ni = 0; ni < 4; ++ni)
            acc[mi][ni] = (f32x4){0.f, 0.f, 0.f, 0.f};

    const int nlo = lane & 15;
    const int q   = lane >> 4;
    const int dh  = q >> 1, dw = q & 1;

    // stage chunk 0 into buffer 0
    #pragma unroll
    for (int i = 0; i < 4; ++i)
        if (act[i])
            async_ld16(gb[i], isB[i] ? &xsb[0][loff[i]] : &als[0][loff[i]]);

    for (int c = 0; c < 32; ++c) {
        __syncthreads();                 // drains vmcnt -> buf[c&1] ready
        const int sel = c & 1;
        if (c < 31) {                    // prefetch next chunk into other buf
            const int ps = sel ^ 1;
            #pragma unroll
            for (int i = 0; i < 4; ++i)
                if (act[i])
                    async_ld16(gb[i] + (size_t)(c+1)*gstep[i],
                               isB[i] ? &xsb[ps][loff[i]] : &als[ps][loff[i]]);
        }
        bf16x8 af[4], bfr[4];
        #pragma unroll
        for (int mi = 0; mi < 4; ++mi)
            af[mi] = *(const bf16x8*)(&als[sel][(wm*64 + mi*16 + nlo)*40 + q*8]);
        #pragma unroll
        for (int ni = 0; ni < 4; ++ni) {
            int a_local = wn*4 + ni;
            bfr[ni] = *(const bf16x8*)(&xsb[sel][((a_local + dh)*17 + (nlo + dw))*8]);
        }
        #pragma unroll
        for (int mi = 0; mi < 4; ++mi)
            #pragma unroll
            for (int ni = 0; ni < 4; ++ni)
                acc[mi][ni] = __builtin_amdgcn_mfma_f32_16x16x32_bf16(
                    af[mi], bfr[ni], acc[mi][ni], 0, 0, 0);
    }

    // ---- epilogue: bias + PReLU ----
    const float pa = prelu_a[0];
    #pragma unroll
    for (int mi = 0; mi < 4; ++mi) {
        #pragma unroll
        for (int reg = 0; reg < 4; ++reg) {
            int co = wm*64 + mi*16 + q*4 + reg;
            float bv = bias[co];
            #pragma unroll
            for (int ni = 0; ni < 4; ++ni) {
                int a_local = wn*4 + ni;
                int oh = 2*(a0 + a_local) + r;
                int ow = 2*(c0 + nlo) + s;
                float v = acc[mi][ni][reg] + bv;
                v = (v >= 0.f) ? v : pa*v;
                out[(((size_t)b*COUT_ + co)*OH_ + oh)*OW_ + ow] = v;
            }
        }
    }
}

// ---------------------------------------------------------------------------
// Middle fallback: round-2 gather-based MFMA deconv (needs only aws in ws).
// ---------------------------------------------------------------------------
__global__ __launch_bounds__(256, 2) void deconv_mfma_gather(
    const float* __restrict__ x,
    const short* __restrict__ aws,
    const float* __restrict__ bias,
    const float* __restrict__ prelu_a,
    float* __restrict__ out)
{
    const int tid  = threadIdx.x;
    const int lane = tid & 63;
    const int wv   = tid >> 6;
    const int wm   = wv & 1, wn = wv >> 1;
    const int nt   = blockIdx.x;
    const int cls  = blockIdx.y;
    const int b    = blockIdx.z;
    const int a0 = (nt >> 2) * 8, c0 = (nt & 3) * 16;
    const int r = cls >> 1, s = cls & 1;

    __shared__ __align__(16) short xs[1280];
    __shared__ __align__(16) short als[5120];

    int goff[5], gstep[5], gok[5];
    #pragma unroll
    for (int i = 0; i < 5; ++i) {
        int e    = tid + i*256;
        int ci_l = e & 7;
        int rc   = e >> 3;
        int row  = rc / 17;
        int col  = rc - row*17;
        int ih   = a0 - 1 + r + row;
        int iw   = c0 - 1 + s + col;
        int ok   = (rc < 153) && ((unsigned)ih < (unsigned)H_)
                              && ((unsigned)iw < (unsigned)W_);
        goff[i]  = ok ? (((b*CIN_ + ci_l)*H_ + ih)*W_ + iw) : 0;
        gstep[i] = ok ? (8*H_*W_) : 0;
        gok[i]   = ok;
    }
    const size_t aws_base = (((size_t)b*4 + cls)*32) * 5120;

    f32x4 acc[4][4];
    #pragma unroll
    for (int mi = 0; mi < 4; ++mi)
        #pragma unroll
        for (int ni = 0; ni < 4; ++ni)
            acc[mi][ni] = (f32x4){0.f, 0.f, 0.f, 0.f};

    const int nlo = lane & 15;
    const int q   = lane >> 4;
    const int dh  = q >> 1, dw = q & 1;

    for (int chunk = 0; chunk < 32; ++chunk) {
        __syncthreads();
        #pragma unroll
        for (int i = 0; i < 5; ++i) {
            float v = x[goff[i] + chunk*gstep[i]];
            v = gok[i] ? v : 0.0f;
            xs[tid + i*256] = f2bf(v);
        }
        {
            const short* src = aws + aws_base + (size_t)chunk*5120;
            #pragma unroll
            for (int i = 0; i < 3; ++i) {
                int idx = wv + i*4;
                if (idx < 10)
                    async_ld16(src + idx*512 + lane*8, als + idx*512);
            }
        }
        __syncthreads();
        bf16x8 af[4], bfr[4];
        #pragma unroll
        for (int mi = 0; mi < 4; ++mi)
            af[mi] = *(const bf16x8*)(als + (wm*64 + mi*16 + nlo)*40 + q*8);
        #pragma unroll
        for (int ni = 0; ni < 4; ++ni) {
            int a_local = wn*4 + ni;
            bfr[ni] = *(const bf16x8*)(xs + ((a_local + dh)*17 + (nlo + dw))*8);
        }
        #pragma unroll
        for (int mi = 0; mi < 4; ++mi)
            #pragma unroll
            for (int ni = 0; ni < 4; ++ni)
                acc[mi][ni] = __builtin_amdgcn_mfma_f32_16x16x32_bf16(
                    af[mi], bfr[ni], acc[mi][ni], 0, 0, 0);
    }

    const float pa = prelu_a[0];
    #pragma unroll
    for (int mi = 0; mi < 4; ++mi) {
        #pragma unroll
        for (int reg = 0; reg < 4; ++reg) {
            int co = wm*64 + mi*16 + q*4 + reg;
            float bv = bias[co];
            #pragma unroll
            for (int ni = 0; ni < 4; ++ni) {
                int a_local = wn*4 + ni;
                int oh = 2*(a0 + a_local) + r;
                int ow = 2*(c0 + nlo) + s;
                float v = acc[mi][ni][reg] + bv;
                v = (v >= 0.f) ? v : pa*v;
                out[(((size_t)b*COUT_ + co)*OH_ + oh)*OW_ + ow] = v;
            }
        }
    }
}

// ---------------------------------------------------------------------------
// Last-resort fallback: fp32 direct kernel, in-kernel weight synthesis, no ws.
// ---------------------------------------------------------------------------
__global__ __launch_bounds__(256) void deconv_fallback(
    const float* __restrict__ x,
    const float* __restrict__ weight,
    const float* __restrict__ tb, const float* __restrict__ tq,
    const float* __restrict__ tn, const float* __restrict__ tx,
    const float* __restrict__ mb, const float* __restrict__ mq,
    const float* __restrict__ mn, const float* __restrict__ mx,
    const float* __restrict__ feat,
    const float* __restrict__ bias, const float* __restrict__ prelu_a,
    float* __restrict__ out)
{
    const int tid    = threadIdx.x;
    const int tile   = blockIdx.x;
    const int coT    = blockIdx.y;
    const int b      = blockIdx.z;
    const int tile_h = tile >> 3, tile_w = tile & 7;
    const int a0 = tile_h * 8;
    const int c0 = tile_w * 8;
    const int co0 = coT * 64;

    const int tco = tid & 15;
    const int tpx = tid >> 4;
    const int rr  = tpx >> 2, rc = tpx & 3;

    __shared__ float xsf[4][100];
    __shared__ float wsh[4][16][64];

    float acc[4][4][4];
    #pragma unroll
    for (int i = 0; i < 4; ++i)
        #pragma unroll
        for (int j = 0; j < 4; ++j)
            #pragma unroll
            for (int c = 0; c < 4; ++c) acc[i][j][c] = 0.f;

    float f0 = feat[b*4 + 0], f1 = feat[b*4 + 1];
    float f2 = feat[b*4 + 2], f3 = feat[b*4 + 3];

    for (int chunk = 0; chunk < CIN_ / 4; ++chunk) {
        const int ci0 = chunk * 4;
        __syncthreads();
        for (int e = tid; e < 400; e += 256) {
            int ci_l = e / 100; int rem = e - ci_l * 100;
            int rI = rem / 10;  int cI = rem - rI * 10;
            int ih = a0 - 1 + rI, iw = c0 - 1 + cI;
            float v = 0.f;
            if ((unsigned)ih < (unsigned)H_ && (unsigned)iw < (unsigned)W_)
                v = x[(((size_t)b * CIN_ + ci0 + ci_l) * H_ + ih) * W_ + iw];
            xsf[ci_l][rem] = v;
        }
        #pragma unroll
        for (int k = 0; k < 4; ++k) {
            int g = tid + k * 256;
            int ci_l = g >> 8; int rrem = g & 255;
            int co_l = rrem >> 2; int tg = (rrem & 3) * 4;
            int cico = (ci0 + ci_l) * COUT_ + co0 + co_l;
            int e = cico * 16 + tg;
            float4 w  = *(const float4*)(weight + e);
            float4 vb = *(const float4*)(tb + e);
            float4 vq = *(const float4*)(tq + e);
            float4 vn = *(const float4*)(tn + e);
            float4 vx = *(const float4*)(tx + e);
            float sb = mb[cico] * f0, sq = mq[cico] * f1;
            float sn = mn[cico] * f2, sx = mx[cico] * f3;
            float4 wvv;
            wvv.x = w.x + sb*vb.x + sq*vq.x + sn*vn.x + sx*vx.x;
            wvv.y = w.y + sb*vb.y + sq*vq.y + sn*vn.y + sx*vx.y;
            wvv.z = w.z + sb*vb.z + sq*vq.z + sn*vn.z + sx*vx.z;
            wvv.w = w.w + sb*vb.w + sq*vq.w + sn*vn.w + sx*vx.w;
            wsh[ci_l][tg + 0][co_l] = wvv.x;
            wsh[ci_l][tg + 1][co_l] = wvv.y;
            wsh[ci_l][tg + 2][co_l] = wvv.z;
            wsh[ci_l][tg + 3][co_l] = wvv.w;
        }
        __syncthreads();
        #pragma unroll
        for (int ci_l = 0; ci_l < 4; ++ci_l) {
            float xpv[4][4];
            #pragma unroll
            for (int i = 0; i < 4; ++i)
                #pragma unroll
                for (int j = 0; j < 4; ++j)
                    xpv[i][j] = xsf[ci_l][(rr*2 + i) * 10 + rc*2 + j];
            #pragma unroll
            for (int kh = 0; kh < 4; ++kh) {
                const int rpar = (kh & 1) ? 0 : 1;
                const int offh = (kh == 0) ? 2 : (kh == 3) ? 0 : 1;
                #pragma unroll
                for (int kw = 0; kw < 4; ++kw) {
                    const int spar = (kw & 1) ? 0 : 1;
                    const int offw = (kw == 0) ? 2 : (kw == 3) ? 0 : 1;
                    float4 wvv = *(const float4*)&wsh[ci_l][kh*4 + kw][tco*4];
                    float wr[4] = {wvv.x, wvv.y, wvv.z, wvv.w};
                    #pragma unroll
                    for (int da = 0; da < 2; ++da)
                        #pragma unroll
                        for (int dc = 0; dc < 2; ++dc) {
                            const float xvv = xpv[da + offh][dc + offw];
                            #pragma unroll
                            for (int cc = 0; cc < 4; ++cc)
                                acc[2*da + rpar][2*dc + spar][cc] =
                                    fmaf(wr[cc], xvv, acc[2*da + rpar][2*dc + spar][cc]);
                        }
                }
            }
        }
    }
    const float pa  = prelu_a[0];
    const int oh0 = tile_h * 16 + rr * 4;
    const int ow0 = tile_w * 16 + rc * 4;
    #pragma unroll
    for (int cc = 0; cc < 4; ++cc) {
        const int co = co0 + tco * 4 + cc;
        const float bv = bias[co];
        #pragma unroll
        for (int dr = 0; dr < 4; ++dr)
            #pragma unroll
            for (int dw2 = 0; dw2 < 4; ++dw2) {
                float v = acc[dr][dw2][cc] + bv;
                v = (v >= 0.f) ? v : pa * v;
                out[(((size_t)b * COUT_ + co) * OH_ + (oh0 + dr)) * OW_ + (ow0 + dw2)] = v;
            }
    }
}

extern "C" void kernel_launch(void* const* d_in, const int* in_sizes, int n_in,
                              void* d_out, int out_size, void* d_ws, size_t ws_size,
                              hipStream_t stream) {
    (void)in_sizes; (void)n_in; (void)out_size;
    const float* x      = (const float*)d_in[0];
    const float* feat   = (const float*)d_in[1];
    const float* weight = (const float*)d_in[2];
    const float* tb     = (const float*)d_in[3];
    const float* tq     = (const float*)d_in[4];
    const float* tn     = (const float*)d_in[5];
    const float* tx     = (const float*)d_in[6];
    const float* mb     = (const float*)d_in[7];
    const float* mq     = (const float*)d_in[8];
    const float* mn     = (const float*)d_in[9];
    const float* mx     = (const float*)d_in[10];
    const float* bias   = (const float*)d_in[11];
    const float* prelu  = (const float*)d_in[12];
    float* out = (float*)d_out;

    const size_t aws_sz = (size_t)B_ * 4 * 32 * 128 * 40 * sizeof(short);   // 20.97 MB
    const size_t xt_sz  = (size_t)B_ * 32 * 66 * 66 * 8 * sizeof(short);    // 35.68 MB

    if (ws_size >= aws_sz + xt_sz) {
        short* aws = (short*)d_ws;
        short* xt  = (short*)((char*)d_ws + aws_sz);
        synth_aws<<<dim3(32, 4, 16), 256, 0, stream>>>(
            weight, tb, tq, tn, tx, mb, mq, mn, mx, feat, aws);
        transform_x<<<dim3(66, 16), 256, 0, stream>>>(x, xt);
        deconv_mfma2<<<dim3(32, 4, 16), 256, 0, stream>>>(
            aws, xt, bias, prelu, out);
    } else if (ws_size >= aws_sz) {
        short* aws = (short*)d_ws;
        synth_aws<<<dim3(32, 4, 16), 256, 0, stream>>>(
            weight, tb, tq, tn, tx, mb, mq, mn, mx, feat, aws);
        deconv_mfma_gather<<<dim3(32, 4, 16), 256, 0, stream>>>(
            x, aws, bias, prelu, out);
    } else {
        deconv_fallback<<<dim3(64, 2, 16), 256, 0, stream>>>(
            x, weight, tb, tq, tn, tx, mb, mq, mn, mx, feat, bias, prelu, out);
    }
}